// Round 10
// baseline (463.152 us; speedup 1.0000x reference)
//
#include <hip/hip_runtime.h>
#include <hip/hip_bf16.h>

typedef __attribute__((ext_vector_type(8))) short bf16x8_t;
typedef __attribute__((ext_vector_type(4))) short bf16x4_t;
typedef __attribute__((ext_vector_type(4))) float f32x4_t;

#define MFMA16 __builtin_amdgcn_mfma_f32_16x16x32_bf16

#if __has_builtin(__builtin_amdgcn_mfma_f32_16x16x16bf16_1k)
#define HAVE_MFMA_K16 1
#define MFMA16K16 __builtin_amdgcn_mfma_f32_16x16x16bf16_1k
#else
#define HAVE_MFMA_K16 0
#endif

__device__ __forceinline__ unsigned short f2bf(float f) {
    return __builtin_bit_cast(unsigned short, __float2bfloat16(f));
}
__device__ __forceinline__ int cvt_pk_bf16(float lo, float hi) {
    int r;
    asm("v_cvt_pk_bf16_f32 %0, %1, %2" : "=v"(r) : "v"(lo), "v"(hi));
    return r;
}

// ---------------- LDS layout: 2 window-groups, one window per group ----------------
// Per group g:
//   slices @ g*49152, per head h @ +h*8192: Q[64][32e] swz | K[64][32e] swz
//     (VT over Q post-S; O[64 rows][192ch] stride 400 over the slices region post-#3)
//   X[64][192] bf16 stride 400B @ XB_OFF + g*25600 (dedicated; no X<->slice alias)
// rowOff[g][64] int @ ROWOFF_OFF.  ~150 KB -> 1 block/CU (register-limited to 12
// waves anyway).
//
// r5-r8 lessons: persistent loops / cross-phase register residency spill past the
// 170-reg cap. r9 lesson: groups must stay PHASE-LOCKED (3 waves/SIMD need
// same-phase bursts to fill a pipe) -> plain __syncthreads everywhere.
// r10 structure: STAGE PIPELINED UNDER QKV (mt-major). Stage iteration it covers
// rows 8it..8it+7; QKV tile mt needs rows 16mt..16mt+15. Intervals:
//   stage rows 0-15 | B | {issue rows16-31 loads, QKV(0), commit} | B |
//   {rows32-47, QKV(1)} | B | {rows48-63, QKV(2)} | B | QKV(3) | ...
// The 2 float4 loads per interval (8 transient VGPRs, single-interval lifetime)
// hide their ~900cyc HBM latency under ~36 MFMA + weight loads.
#define XB_OFF     98304
#define ROWOFF_OFF 149504
#define SMEM_BYTES 150016

__device__ __forceinline__ int qk_byte(int row, int d) {
    return row * 64 + ((((d >> 3) ^ ((row >> 1) & 3)) << 4) | ((d & 7) << 1));
}
__device__ __forceinline__ int vt_byte(int d, int tok) {
    return d * 128 + ((((tok >> 3) ^ (d & 7)) << 4) | ((tok & 7) << 1));
}

__global__ void prep_weights(const float* __restrict__ qkv_w, const float* __restrict__ proj_w,
                             unsigned short* __restrict__ wqkvT, unsigned short* __restrict__ wprojT)
{
    int i = blockIdx.x * 256 + threadIdx.x;
    if (i < 576 * 192) {            // wqkvT[n][k] = qkv_w[k][n]
        int n = i / 192, k = i - n * 192;
        wqkvT[i] = f2bf(qkv_w[k * 576 + n]);
    }
    if (i < 192 * 192) {            // wprojT[n][k] = proj_w[k][n]
        int n = i / 192, k = i - n * 192;
        wprojT[i] = f2bf(proj_w[k * 192 + n]);
    }
}

// biasT[wt][h][frag=mk*4+nq][lane] = float4 over r (0 outside 49x49)
__global__ void prep_bias(const float* __restrict__ rel_table, float* __restrict__ biasT)
{
    int i = blockIdx.x * 256 + threadIdx.x;    // 0..24575
    if (i >= 4 * 6 * 16 * 64) return;
    int ln  = i & 63;
    int f   = (i >> 6) & 15;
    int h   = (i >> 10) % 6;
    int wt  = i / 6144;                        // 0..3 = borderH*2 + borderW
    int l15 = ln & 15, lg = ln >> 4;
    int mk  = f >> 2, nq = f & 3;
    int qt  = nq * 16 + l15;
    bool bh = (wt & 2) != 0, bw = (wt & 1) != 0;
    float4 o = {0.f, 0.f, 0.f, 0.f};
    float* po = (float*)&o;
    int iq = qt / 7, jq = qt - iq * 7;
    int regq = (bh ? ((iq < 4) ? 3 : 6) : 0) + (bw ? ((jq < 4) ? 1 : 2) : 0);
    for (int r = 0; r < 4; ++r) {
        int kt = mk * 16 + lg * 4 + r;
        if (kt < 49 && qt < 49) {
            int ik = kt / 7, jk = kt - ik * 7;
            int idx = (iq - ik + 6) * 13 + (jq - jk + 6);
            int regk = (bh ? ((ik < 4) ? 3 : 6) : 0) + (bw ? ((jk < 4) ? 1 : 2) : 0);
            po[r] = rel_table[idx * 6 + h] + ((regk != regq) ? -100.0f : 0.0f);
        }
    }
    ((float4*)biasT)[i] = o;
}

// stage helpers: ISSUE computes addresses, writes rowOff, issues the global load
// (or writes zeros for pad rows); COMMIT cvt+writes after the covering compute.
#define STAGE_ISSUE(IT, V, DST, HAS)                                              \
    {                                                                             \
        int idx_ = tg + (IT) * 384;                                               \
        int n_   = idx_ / 48;                                                     \
        int c4_  = idx_ - n_ * 48;                                                \
        DST = xb + n_ * 400 + c4_ * 8;                                            \
        HAS = (n_ < 49);                                                          \
        if (HAS) {                                                                \
            int i_ = n_ / 7, j_ = n_ - i_ * 7;                                    \
            int sh_ = wh * 7 + i_ + 3; if (sh_ >= 56) sh_ -= 56;                  \
            int sw_ = ww * 7 + j_ + 3; if (sw_ >= 56) sw_ -= 56;                  \
            int ro_ = ((b * 56 + sh_) * 56 + sw_) * 192;                          \
            if (c4_ == 0) rowOff[n_] = ro_;                                       \
            V = *(const float4*)(x + ro_ + c4_ * 4);                              \
        } else {                                                                  \
            *(int2*)(smem + DST) = make_int2(0, 0);                               \
        }                                                                         \
    }
#define STAGE_COMMIT(V, DST, HAS)                                                 \
    if (HAS) {                                                                    \
        int2 pk_;                                                                 \
        pk_.x = cvt_pk_bf16(V.x, V.y);                                            \
        pk_.y = cvt_pk_bf16(V.z, V.w);                                            \
        *(int2*)(smem + DST) = pk_;                                               \
    }

// one QKV row-tile: 6 ks chunks, af from staged X rows MT*16..MT*16+15
#define QKV_MT(MT)                                                                \
    {                                                                             \
        _Pragma("unroll")                                                         \
        for (int ks = 0; ks < 6; ++ks) {                                          \
            bf16x8_t af = *(const bf16x8_t*)(smem + xb + ((MT) * 16 + l15) * 400  \
                                             + (ks * 32 + lg * 8) * 2);           \
            bf16x8_t bfv[6];                                                      \
            _Pragma("unroll")                                                     \
            for (int nt = 0; nt < 6; ++nt)                                        \
                bfv[nt] = *(const bf16x8_t*)(wqkvT + ((nt >> 1) * 192 + h * 32    \
                              + (nt & 1) * 16 + l15) * 192 + ks * 32 + lg * 8);   \
            __builtin_amdgcn_s_setprio(1);                                        \
            _Pragma("unroll")                                                     \
            for (int nt = 0; nt < 6; ++nt)                                        \
                accq[MT][nt] = MFMA16(af, bfv[nt], accq[MT][nt], 0, 0, 0);        \
            __builtin_amdgcn_s_setprio(0);                                        \
        }                                                                         \
    }

__global__ __launch_bounds__(768, 3)
void swin_fused(const float* __restrict__ x,
                const float* __restrict__ qkv_b,
                const float* __restrict__ proj_b,
                const unsigned short* __restrict__ wqkvT,
                const unsigned short* __restrict__ wprojT,
                const float* __restrict__ biasT,
                float* __restrict__ out)
{
    __shared__ unsigned char smem[SMEM_BYTES];

    const int tid = threadIdx.x;
    const int wv  = tid >> 6;          // 0..11
    const int g   = (wv >= 6) ? 1 : 0; // window group within block
    const int h   = wv - 6 * g;        // head 0..5
    const int ln  = tid & 63;
    const int l15 = ln & 15;
    const int lg  = ln >> 4;           // 0..3
    const int tg  = tid - g * 384;     // thread id within group, 0..383

    const int bw  = blockIdx.x * 2 + g;    // window id 0..4095
    const int b   = bw >> 6;
    const int win = bw & 63;
    const int wh  = win >> 3;
    const int ww  = win & 7;
    const int wt  = ((wh == 7) ? 2 : 0) | ((ww == 7) ? 1 : 0);

    const unsigned gbase = g * 49152;
    const unsigned hbase = gbase + h * 8192;
    const unsigned xb    = XB_OFF + g * 25600;
    int* rowOff = (int*)(smem + ROWOFF_OFF + g * 256);
    const f32x4_t zero4 = {0.f, 0.f, 0.f, 0.f};

    // ---------------- pipelined stage + QKV ----------------
    f32x4_t accq[4][6];
#pragma unroll
    for (int mt = 0; mt < 4; ++mt)
#pragma unroll
        for (int nt = 0; nt < 6; ++nt) accq[mt][nt] = zero4;

    {   // interval 0: stage rows 0-15
        float4 va, vb_; unsigned da, db; bool ha, hb;
        STAGE_ISSUE(0, va, da, ha);
        STAGE_ISSUE(1, vb_, db, hb);
        STAGE_COMMIT(va, da, ha);
        STAGE_COMMIT(vb_, db, hb);
    }
    __syncthreads();                       // B1: rows 0-15 staged

    {   // interval 1: rows 16-31 in flight under QKV(0)
        float4 va, vb_; unsigned da, db; bool ha, hb;
        STAGE_ISSUE(2, va, da, ha);
        STAGE_ISSUE(3, vb_, db, hb);
        QKV_MT(0);
        STAGE_COMMIT(va, da, ha);
        STAGE_COMMIT(vb_, db, hb);
    }
    __syncthreads();                       // B2: rows 16-31 staged

    {   // interval 2: rows 32-47 in flight under QKV(1)
        float4 va, vb_; unsigned da, db; bool ha, hb;
        STAGE_ISSUE(4, va, da, ha);
        STAGE_ISSUE(5, vb_, db, hb);
        QKV_MT(1);
        STAGE_COMMIT(va, da, ha);
        STAGE_COMMIT(vb_, db, hb);
    }
    __syncthreads();                       // B3: rows 32-47 staged

    {   // interval 3: rows 48-63 in flight under QKV(2)
        float4 va, vb_; unsigned da, db; bool ha, hb;
        STAGE_ISSUE(6, va, da, ha);
        STAGE_ISSUE(7, vb_, db, hb);
        QKV_MT(2);
        STAGE_COMMIT(va, da, ha);
        STAGE_COMMIT(vb_, db, hb);
    }
    __syncthreads();                       // B4: rows 48-63 staged

    QKV_MT(3);

    // pack V to bf16 (+bias) -> 16 dwords held in regs through S phase
    int vbf[4][2][2];
#pragma unroll
    for (int nv = 0; nv < 2; ++nv) {
        float bb = qkv_b[384 + h * 32 + nv * 16 + l15];
#pragma unroll
        for (int mt = 0; mt < 4; ++mt) {
            vbf[mt][nv][0] = cvt_pk_bf16(accq[mt][4 + nv][0] + bb, accq[mt][4 + nv][1] + bb);
            vbf[mt][nv][1] = cvt_pk_bf16(accq[mt][4 + nv][2] + bb, accq[mt][4 + nv][3] + bb);
        }
    }
    // (no barrier: X is dedicated; below touches only this wave's private head
    //  slice or read-only data, until #3)

    // scatter Q,K (+bias, bf16) into wave-private slice
#pragma unroll
    for (int nt = 0; nt < 4; ++nt) {
        int part = nt >> 1;                    // 0=q, 1=k
        int d    = (nt & 1) * 16 + l15;
        float bb = qkv_b[part * 192 + h * 32 + d];
        unsigned base = hbase + part * 4096;
#pragma unroll
        for (int mt = 0; mt < 4; ++mt)
#pragma unroll
            for (int r = 0; r < 4; ++r) {
                int row = mt * 16 + lg * 4 + r;
                *(unsigned short*)(smem + base + qk_byte(row, d)) = f2bf(accq[mt][nt][r] + bb);
            }
    }
    __builtin_amdgcn_sched_barrier(0);   // keep S-reads after scatter writes

    // ---------------- S^T = K Q^T (wave-private, rows=kt, cols=qt) ----------------
    f32x4_t s[4][4];
    {
        bf16x8_t kf[4], qf[4];
#pragma unroll
        for (int mk = 0; mk < 4; ++mk) {
            int row = mk * 16 + l15;
            kf[mk] = *(const bf16x8_t*)(smem + hbase + 4096 + row * 64 + ((lg ^ ((row >> 1) & 3)) << 4));
        }
#pragma unroll
        for (int nq = 0; nq < 4; ++nq) {
            int row = nq * 16 + l15;
            qf[nq] = *(const bf16x8_t*)(smem + hbase + row * 64 + ((lg ^ ((row >> 1) & 3)) << 4));
        }
        __builtin_amdgcn_s_setprio(1);
#pragma unroll
        for (int mk = 0; mk < 4; ++mk)
#pragma unroll
            for (int nq = 0; nq < 4; ++nq)
                s[mk][nq] = MFMA16(kf[mk], qf[nq], zero4, 0, 0, 0);
        __builtin_amdgcn_s_setprio(0);
    }
    __builtin_amdgcn_sched_barrier(0);   // Q reads complete before VT overwrites Q

    // write VT[32][64] over Q slice (wave-private; in-wave DS ordering)
#pragma unroll
    for (int nv = 0; nv < 2; ++nv) {
        int d = nv * 16 + l15;
#pragma unroll
        for (int mt = 0; mt < 4; ++mt) {
            int tok = mt * 16 + lg * 4;
            *(int2*)(smem + hbase + vt_byte(d, tok)) = make_int2(vbf[mt][nv][0], vbf[mt][nv][1]);
        }
    }

    // prefetch bias+mask fragments (L2-hot, coalesced): bv4[mk][nq] over r
    float4 bv4[4][4];
    {
        const float4* bp = (const float4*)biasT + (wt * 6 + h) * 16 * 64 + ln;
#pragma unroll
        for (int mk = 0; mk < 4; ++mk)
#pragma unroll
            for (int nq = 0; nq < 4; ++nq)
                bv4[mk][nq] = bp[(mk * 4 + nq) * 64];
    }

    // ---------------- softmax over kt (no max pass: |C*s| << 1) ----------------
    // fused: w = pack(s*inv + bias) in one fmaf pass (bias/mask added post-softmax)
    const float C = 0.17677669529663687f * 1.4426950408889634f;  // scale * log2(e)
    int w[4][4][2];
#pragma unroll
    for (int nq = 0; nq < 4; ++nq) {
        float sum = 0.f;
#pragma unroll
        for (int mk = 0; mk < 4; ++mk)
#pragma unroll
            for (int r = 0; r < 4; ++r) {
                int kt = mk * 16 + lg * 4 + r;
                float e = (kt < 49) ? __builtin_amdgcn_exp2f(C * s[mk][nq][r]) : 0.0f;
                s[mk][nq][r] = e;
                sum += e;
            }
        sum += __shfl_xor(sum, 16);
        sum += __shfl_xor(sum, 32);
        float inv = __builtin_amdgcn_rcpf(sum);
#pragma unroll
        for (int mk = 0; mk < 4; ++mk) {
            float v0 = fmaf(s[mk][nq][0], inv, bv4[mk][nq].x);
            float v1 = fmaf(s[mk][nq][1], inv, bv4[mk][nq].y);
            float v2 = fmaf(s[mk][nq][2], inv, bv4[mk][nq].z);
            float v3 = fmaf(s[mk][nq][3], inv, bv4[mk][nq].w);
            w[mk][nq][0] = cvt_pk_bf16(v0, v1);
            w[mk][nq][1] = cvt_pk_bf16(v2, v3);
        }
    }

    // ---------------- O^T = VT * attn ----------------
    f32x4_t o[2][4];
#pragma unroll
    for (int md = 0; md < 2; ++md)
#pragma unroll
        for (int nq = 0; nq < 4; ++nq) o[md][nq] = zero4;

#if HAVE_MFMA_K16
    // w[mk][nq] is already a valid 16x16x16 B-operand (lane l15 = qt col, k = lg*4+r)
#pragma unroll
    for (int mk = 0; mk < 4; ++mk) {
        bf16x4_t vt2[2];
#pragma unroll
        for (int md = 0; md < 2; ++md) {
            int d = md * 16 + l15;
            vt2[md] = *(const bf16x4_t*)(smem + hbase + vt_byte(d, mk * 16 + lg * 4));
        }
        __builtin_amdgcn_s_setprio(1);
#pragma unroll
        for (int nq = 0; nq < 4; ++nq) {
            bf16x4_t wb = __builtin_bit_cast(bf16x4_t, make_int2(w[mk][nq][0], w[mk][nq][1]));
#pragma unroll
            for (int md = 0; md < 2; ++md)
                o[md][nq] = MFMA16K16(vt2[md], wb, o[md][nq], 0, 0, 0);
        }
        __builtin_amdgcn_s_setprio(0);
    }
#else
    // fallback: A staged per kt-half in dead K slice, K=32 MFMA
    const unsigned Abase = hbase + 4096;   // over K (dead after S)
#pragma unroll
    for (int ks = 0; ks < 2; ++ks) {
#pragma unroll
        for (int mh = 0; mh < 2; ++mh) {
            int mk = ks * 2 + mh;
            int d  = mh * 16 + lg * 4;
#pragma unroll
            for (int nq = 0; nq < 4; ++nq) {
                int qt = nq * 16 + l15;
                *(int2*)(smem + Abase + qk_byte(qt, d)) = make_int2(w[mk][nq][0], w[mk][nq][1]);
            }
        }
        __builtin_amdgcn_sched_barrier(0);   // A writes before reads
        bf16x8_t vf[2], bfr[4];
#pragma unroll
        for (int md = 0; md < 2; ++md) {
            int d = md * 16 + l15;
            vf[md] = *(const bf16x8_t*)(smem + hbase + d * 128 + (((ks * 4 + lg) ^ (d & 7)) << 4));
        }
#pragma unroll
        for (int nq = 0; nq < 4; ++nq) {
            int qt = nq * 16 + l15;
            bfr[nq] = *(const bf16x8_t*)(smem + Abase + qt * 64 + ((lg ^ ((qt >> 1) & 3)) << 4));
        }
        __builtin_amdgcn_s_setprio(1);
#pragma unroll
        for (int nq = 0; nq < 4; ++nq)
#pragma unroll
            for (int md = 0; md < 2; ++md)
                o[md][nq] = MFMA16(vf[md], bfr[nq], o[md][nq], 0, 0, 0);
        __builtin_amdgcn_s_setprio(0);
        __builtin_amdgcn_sched_barrier(0);   // half reads done before next-half writes
    }
#endif
    __syncthreads();   // #3: all done with slices; repurpose LDS for O

    // write O^T -> O_lds[qt][192ch] stride 400B, packed b64
#pragma unroll
    for (int md = 0; md < 2; ++md)
#pragma unroll
        for (int nq = 0; nq < 4; ++nq) {
            int qt = nq * 16 + l15;
            int ch = h * 32 + md * 16 + lg * 4;
            int d0 = cvt_pk_bf16(o[md][nq][0], o[md][nq][1]);
            int d1 = cvt_pk_bf16(o[md][nq][2], o[md][nq][3]);
            *(int2*)(smem + gbase + qt * 400 + ch * 2) = make_int2(d0, d1);
        }
    __syncthreads();   // #4: O ready

    // ---------------- proj: Y = O @ proj_w^T + b, wave owns 32 cols ----------------
    f32x4_t y[4][2];
#pragma unroll
    for (int mt = 0; mt < 4; ++mt) { y[mt][0] = zero4; y[mt][1] = zero4; }
#pragma unroll
    for (int ks = 0; ks < 6; ++ks) {
        bf16x8_t aa[4], bb[2];
#pragma unroll
        for (int mt = 0; mt < 4; ++mt)
            aa[mt] = *(const bf16x8_t*)(smem + gbase + (mt * 16 + l15) * 400 + (ks * 32 + lg * 8) * 2);
#pragma unroll
        for (int nt = 0; nt < 2; ++nt)
            bb[nt] = *(const bf16x8_t*)(wprojT + (h * 32 + nt * 16 + l15) * 192 + ks * 32 + lg * 8);
        __builtin_amdgcn_s_setprio(1);
#pragma unroll
        for (int mt = 0; mt < 4; ++mt)
#pragma unroll
            for (int nt = 0; nt < 2; ++nt)
                y[mt][nt] = MFMA16(aa[mt], bb[nt], y[mt][nt], 0, 0, 0);
        __builtin_amdgcn_s_setprio(0);
    }
    // epilogue: +proj_b, scatter via precomputed rowOff
    float pb0 = proj_b[h * 32 + l15];
    float pb1 = proj_b[h * 32 + 16 + l15];
#pragma unroll
    for (int mt = 0; mt < 4; ++mt)
#pragma unroll
        for (int r = 0; r < 4; ++r) {
            int row = mt * 16 + lg * 4 + r;
            if (row < 49) {
                int ro = rowOff[row];
                out[ro + h * 32 + l15]      = y[mt][0][r] + pb0;
                out[ro + h * 32 + 16 + l15] = y[mt][1][r] + pb1;
            }
        }
}

extern "C" void kernel_launch(void* const* d_in, const int* in_sizes, int n_in,
                              void* d_out, int out_size, void* d_ws, size_t ws_size,
                              hipStream_t stream) {
    const float* x         = (const float*)d_in[0];
    const float* qkv_w     = (const float*)d_in[1];
    const float* qkv_b     = (const float*)d_in[2];
    const float* rel_table = (const float*)d_in[3];
    const float* proj_w    = (const float*)d_in[4];
    const float* proj_b    = (const float*)d_in[5];
    float* out = (float*)d_out;

    unsigned short* wqkvT  = (unsigned short*)d_ws;            // [576][192] bf16 = 221184 B
    unsigned short* wprojT = wqkvT + 576 * 192;                // [192][192] bf16 =  73728 B
    float* biasT = (float*)((char*)d_ws + 294912);             // [4][6][16][64] float4 = 393216 B

    prep_weights<<<576, 256, 0, stream>>>(qkv_w, proj_w, wqkvT, wprojT);
    prep_bias<<<96, 256, 0, stream>>>(rel_table, biasT);
    swin_fused<<<2048, 768, 0, stream>>>(x, qkv_b, proj_b, wqkvT, wprojT, biasT, out);
}

// Round 11
// 277.693 us; speedup vs baseline: 1.6679x; 1.6679x over previous
//
#include <hip/hip_runtime.h>
#include <hip/hip_bf16.h>

typedef __attribute__((ext_vector_type(8))) short bf16x8_t;
typedef __attribute__((ext_vector_type(4))) short bf16x4_t;
typedef __attribute__((ext_vector_type(4))) float f32x4_t;

#define MFMA16 __builtin_amdgcn_mfma_f32_16x16x32_bf16

#if __has_builtin(__builtin_amdgcn_mfma_f32_16x16x16bf16_1k)
#define HAVE_MFMA_K16 1
#define MFMA16K16 __builtin_amdgcn_mfma_f32_16x16x16bf16_1k
#else
#define HAVE_MFMA_K16 0
#endif

__device__ __forceinline__ unsigned short f2bf(float f) {
    return __builtin_bit_cast(unsigned short, __float2bfloat16(f));
}
__device__ __forceinline__ int cvt_pk_bf16(float lo, float hi) {
    int r;
    asm("v_cvt_pk_bf16_f32 %0, %1, %2" : "=v"(r) : "v"(lo), "v"(hi));
    return r;
}

// ---------------- LDS layout: 2 window-groups, one window per group ----------------
// Per group g:
//   slices @ g*49152, per head h @ +h*8192: Q[64][32e] swz | K[64][32e] swz
//     (VT over Q post-S; O[64 rows][192ch] stride 400 over the slices region post-#3)
//   X[64][192] bf16 stride 400B @ XB_OFF + g*25600 (dedicated; no X<->slice alias)
// rowOff[g][64] int @ ROWOFF_OFF.  ~150 KB -> 1 block/CU (register-limited to 12
// waves anyway).
//
// Register law (r1/r2/r5-r8/r10, 5x confirmed): peak live > ~165 VGPRs => the
// allocator spills ENTIRE arrays (~90 dwords -> ~500MB scratch traffic). QKV with
// 6 merged outputs (96 acc) + stage transients broke this (r10). Fix here: QKV
// split into pass1=[q0,q1,k0,k1] (64 acc) pipelined with the stage, and
// pass2=[v0,v1] (32 acc) after. Peak ~112. Interval/barrier skeleton is
// correctness-validated by r10 (passed, absmax 1.0).
// r9 lesson: groups stay PHASE-LOCKED -> plain __syncthreads everywhere.
#define XB_OFF     98304
#define ROWOFF_OFF 149504
#define SMEM_BYTES 150016

__device__ __forceinline__ int qk_byte(int row, int d) {
    return row * 64 + ((((d >> 3) ^ ((row >> 1) & 3)) << 4) | ((d & 7) << 1));
}
__device__ __forceinline__ int vt_byte(int d, int tok) {
    return d * 128 + ((((tok >> 3) ^ (d & 7)) << 4) | ((tok & 7) << 1));
}

__global__ void prep_weights(const float* __restrict__ qkv_w, const float* __restrict__ proj_w,
                             unsigned short* __restrict__ wqkvT, unsigned short* __restrict__ wprojT)
{
    int i = blockIdx.x * 256 + threadIdx.x;
    if (i < 576 * 192) {            // wqkvT[n][k] = qkv_w[k][n]
        int n = i / 192, k = i - n * 192;
        wqkvT[i] = f2bf(qkv_w[k * 576 + n]);
    }
    if (i < 192 * 192) {            // wprojT[n][k] = proj_w[k][n]
        int n = i / 192, k = i - n * 192;
        wprojT[i] = f2bf(proj_w[k * 192 + n]);
    }
}

// biasT[wt][h][frag=mk*4+nq][lane] = float4 over r (0 outside 49x49)
__global__ void prep_bias(const float* __restrict__ rel_table, float* __restrict__ biasT)
{
    int i = blockIdx.x * 256 + threadIdx.x;    // 0..24575
    if (i >= 4 * 6 * 16 * 64) return;
    int ln  = i & 63;
    int f   = (i >> 6) & 15;
    int h   = (i >> 10) % 6;
    int wt  = i / 6144;                        // 0..3 = borderH*2 + borderW
    int l15 = ln & 15, lg = ln >> 4;
    int mk  = f >> 2, nq = f & 3;
    int qt  = nq * 16 + l15;
    bool bh = (wt & 2) != 0, bw = (wt & 1) != 0;
    float4 o = {0.f, 0.f, 0.f, 0.f};
    float* po = (float*)&o;
    int iq = qt / 7, jq = qt - iq * 7;
    int regq = (bh ? ((iq < 4) ? 3 : 6) : 0) + (bw ? ((jq < 4) ? 1 : 2) : 0);
    for (int r = 0; r < 4; ++r) {
        int kt = mk * 16 + lg * 4 + r;
        if (kt < 49 && qt < 49) {
            int ik = kt / 7, jk = kt - ik * 7;
            int idx = (iq - ik + 6) * 13 + (jq - jk + 6);
            int regk = (bh ? ((ik < 4) ? 3 : 6) : 0) + (bw ? ((jk < 4) ? 1 : 2) : 0);
            po[r] = rel_table[idx * 6 + h] + ((regk != regq) ? -100.0f : 0.0f);
        }
    }
    ((float4*)biasT)[i] = o;
}

// stage helpers: ISSUE computes addresses, writes rowOff, issues the global load
// (or writes zeros for pad rows); COMMIT cvt+writes after the covering compute.
#define STAGE_ISSUE(IT, V, DST, HAS)                                              \
    {                                                                             \
        int idx_ = tg + (IT) * 384;                                               \
        int n_   = idx_ / 48;                                                     \
        int c4_  = idx_ - n_ * 48;                                                \
        DST = xb + n_ * 400 + c4_ * 8;                                            \
        HAS = (n_ < 49);                                                          \
        if (HAS) {                                                                \
            int i_ = n_ / 7, j_ = n_ - i_ * 7;                                    \
            int sh_ = wh * 7 + i_ + 3; if (sh_ >= 56) sh_ -= 56;                  \
            int sw_ = ww * 7 + j_ + 3; if (sw_ >= 56) sw_ -= 56;                  \
            int ro_ = ((b * 56 + sh_) * 56 + sw_) * 192;                          \
            if (c4_ == 0) rowOff[n_] = ro_;                                       \
            V = *(const float4*)(x + ro_ + c4_ * 4);                              \
        } else {                                                                  \
            *(int2*)(smem + DST) = make_int2(0, 0);                               \
        }                                                                         \
    }
#define STAGE_COMMIT(V, DST, HAS)                                                 \
    if (HAS) {                                                                    \
        int2 pk_;                                                                 \
        pk_.x = cvt_pk_bf16(V.x, V.y);                                            \
        pk_.y = cvt_pk_bf16(V.z, V.w);                                            \
        *(int2*)(smem + DST) = pk_;                                               \
    }

// QKV pass1 row-tile: outputs nt=0..3 = [q0,q1,k0,k1], af from rows MT*16..+15
#define QKV1_MT(MT)                                                               \
    {                                                                             \
        _Pragma("unroll")                                                         \
        for (int ks = 0; ks < 6; ++ks) {                                          \
            bf16x8_t af = *(const bf16x8_t*)(smem + xb + ((MT) * 16 + l15) * 400  \
                                             + (ks * 32 + lg * 8) * 2);           \
            bf16x8_t bfv[4];                                                      \
            _Pragma("unroll")                                                     \
            for (int nt = 0; nt < 4; ++nt)                                        \
                bfv[nt] = *(const bf16x8_t*)(wqkvT + ((nt >> 1) * 192 + h * 32    \
                              + (nt & 1) * 16 + l15) * 192 + ks * 32 + lg * 8);   \
            __builtin_amdgcn_s_setprio(1);                                        \
            _Pragma("unroll")                                                     \
            for (int nt = 0; nt < 4; ++nt)                                        \
                acc1[MT][nt] = MFMA16(af, bfv[nt], acc1[MT][nt], 0, 0, 0);        \
            __builtin_amdgcn_s_setprio(0);                                        \
        }                                                                         \
    }

__global__ __launch_bounds__(768, 3)
void swin_fused(const float* __restrict__ x,
                const float* __restrict__ qkv_b,
                const float* __restrict__ proj_b,
                const unsigned short* __restrict__ wqkvT,
                const unsigned short* __restrict__ wprojT,
                const float* __restrict__ biasT,
                float* __restrict__ out)
{
    __shared__ unsigned char smem[SMEM_BYTES];

    const int tid = threadIdx.x;
    const int wv  = tid >> 6;          // 0..11
    const int g   = (wv >= 6) ? 1 : 0; // window group within block
    const int h   = wv - 6 * g;        // head 0..5
    const int ln  = tid & 63;
    const int l15 = ln & 15;
    const int lg  = ln >> 4;           // 0..3
    const int tg  = tid - g * 384;     // thread id within group, 0..383

    const int bw  = blockIdx.x * 2 + g;    // window id 0..4095
    const int b   = bw >> 6;
    const int win = bw & 63;
    const int wh  = win >> 3;
    const int ww  = win & 7;
    const int wt  = ((wh == 7) ? 2 : 0) | ((ww == 7) ? 1 : 0);

    const unsigned gbase = g * 49152;
    const unsigned hbase = gbase + h * 8192;
    const unsigned xb    = XB_OFF + g * 25600;
    int* rowOff = (int*)(smem + ROWOFF_OFF + g * 256);
    const f32x4_t zero4 = {0.f, 0.f, 0.f, 0.f};

    // ---------------- pipelined stage + QKV pass1 (q0,q1,k0,k1: 64 acc regs) ----------
    f32x4_t acc1[4][4];
#pragma unroll
    for (int mt = 0; mt < 4; ++mt)
#pragma unroll
        for (int nt = 0; nt < 4; ++nt) acc1[mt][nt] = zero4;

    {   // interval 0: stage rows 0-15 (only 2 loads exposed)
        float4 va, vb_; unsigned da, db; bool ha, hb;
        STAGE_ISSUE(0, va, da, ha);
        STAGE_ISSUE(1, vb_, db, hb);
        STAGE_COMMIT(va, da, ha);
        STAGE_COMMIT(vb_, db, hb);
    }
    __syncthreads();                       // B1: rows 0-15 staged

    {   // interval 1: rows 16-31 in flight under QKV1(0)
        float4 va, vb_; unsigned da, db; bool ha, hb;
        STAGE_ISSUE(2, va, da, ha);
        STAGE_ISSUE(3, vb_, db, hb);
        QKV1_MT(0);
        STAGE_COMMIT(va, da, ha);
        STAGE_COMMIT(vb_, db, hb);
    }
    __syncthreads();                       // B2: rows 16-31 staged

    {   // interval 2: rows 32-47 in flight under QKV1(1)
        float4 va, vb_; unsigned da, db; bool ha, hb;
        STAGE_ISSUE(4, va, da, ha);
        STAGE_ISSUE(5, vb_, db, hb);
        QKV1_MT(1);
        STAGE_COMMIT(va, da, ha);
        STAGE_COMMIT(vb_, db, hb);
    }
    __syncthreads();                       // B3: rows 32-47 staged

    {   // interval 3: rows 48-63 in flight under QKV1(2)
        float4 va, vb_; unsigned da, db; bool ha, hb;
        STAGE_ISSUE(6, va, da, ha);
        STAGE_ISSUE(7, vb_, db, hb);
        QKV1_MT(2);
        STAGE_COMMIT(va, da, ha);
        STAGE_COMMIT(vb_, db, hb);
    }
    __syncthreads();                       // B4: rows 48-63 staged

    QKV1_MT(3);

    // pack Q,K (+bias) to bf16 dwords; acc1 dies here (32 dwords live)
    int pkq[4][2][2], pkk[4][2][2];
#pragma unroll
    for (int nt2 = 0; nt2 < 2; ++nt2) {
        float bq = qkv_b[h * 32 + nt2 * 16 + l15];
        float bk = qkv_b[192 + h * 32 + nt2 * 16 + l15];
#pragma unroll
        for (int mt = 0; mt < 4; ++mt) {
            pkq[mt][nt2][0] = cvt_pk_bf16(acc1[mt][nt2][0] + bq, acc1[mt][nt2][1] + bq);
            pkq[mt][nt2][1] = cvt_pk_bf16(acc1[mt][nt2][2] + bq, acc1[mt][nt2][3] + bq);
            pkk[mt][nt2][0] = cvt_pk_bf16(acc1[mt][2 + nt2][0] + bk, acc1[mt][2 + nt2][1] + bk);
            pkk[mt][nt2][1] = cvt_pk_bf16(acc1[mt][2 + nt2][2] + bk, acc1[mt][2 + nt2][3] + bk);
        }
    }

    // ---------------- QKV pass2: V (32 acc regs), X fully staged ----------------
    int vbf[4][2][2];
    {
        f32x4_t acc2[4][2];
#pragma unroll
        for (int mt = 0; mt < 4; ++mt) { acc2[mt][0] = zero4; acc2[mt][1] = zero4; }
#pragma unroll
        for (int ks = 0; ks < 6; ++ks) {
            bf16x8_t af[4];
#pragma unroll
            for (int mt = 0; mt < 4; ++mt)
                af[mt] = *(const bf16x8_t*)(smem + xb + (mt * 16 + l15) * 400 + (ks * 32 + lg * 8) * 2);
            bf16x8_t bfv[2];
#pragma unroll
            for (int nv = 0; nv < 2; ++nv)
                bfv[nv] = *(const bf16x8_t*)(wqkvT + (2 * 192 + h * 32 + nv * 16 + l15) * 192 + ks * 32 + lg * 8);
            __builtin_amdgcn_s_setprio(1);
#pragma unroll
            for (int nv = 0; nv < 2; ++nv)
#pragma unroll
                for (int mt = 0; mt < 4; ++mt)
                    acc2[mt][nv] = MFMA16(af[mt], bfv[nv], acc2[mt][nv], 0, 0, 0);
            __builtin_amdgcn_s_setprio(0);
        }
#pragma unroll
        for (int nv = 0; nv < 2; ++nv) {
            float bb = qkv_b[384 + h * 32 + nv * 16 + l15];
#pragma unroll
            for (int mt = 0; mt < 4; ++mt) {
                vbf[mt][nv][0] = cvt_pk_bf16(acc2[mt][nv][0] + bb, acc2[mt][nv][1] + bb);
                vbf[mt][nv][1] = cvt_pk_bf16(acc2[mt][nv][2] + bb, acc2[mt][nv][3] + bb);
            }
        }
    }

    // scatter pre-packed Q,K into wave-private swizzled slices (lo/hi b16 writes)
#pragma unroll
    for (int nt = 0; nt < 4; ++nt) {
        const int part = nt >> 1, nt2 = nt & 1;
        const int d = nt2 * 16 + l15;
        const unsigned base = hbase + part * 4096;
#pragma unroll
        for (int mt = 0; mt < 4; ++mt)
#pragma unroll
            for (int p = 0; p < 2; ++p) {
                int row = mt * 16 + lg * 4 + 2 * p;
                unsigned v = (unsigned)(part ? pkk[mt][nt2][p] : pkq[mt][nt2][p]);
                *(unsigned short*)(smem + base + qk_byte(row, d))     = (unsigned short)(v & 0xffffu);
                *(unsigned short*)(smem + base + qk_byte(row + 1, d)) = (unsigned short)(v >> 16);
            }
    }
    __builtin_amdgcn_sched_barrier(0);   // keep S-reads after scatter writes

    // ---------------- S^T = K Q^T (wave-private, rows=kt, cols=qt) ----------------
    f32x4_t s[4][4];
    {
        bf16x8_t kf[4], qf[4];
#pragma unroll
        for (int mk = 0; mk < 4; ++mk) {
            int row = mk * 16 + l15;
            kf[mk] = *(const bf16x8_t*)(smem + hbase + 4096 + row * 64 + ((lg ^ ((row >> 1) & 3)) << 4));
        }
#pragma unroll
        for (int nq = 0; nq < 4; ++nq) {
            int row = nq * 16 + l15;
            qf[nq] = *(const bf16x8_t*)(smem + hbase + row * 64 + ((lg ^ ((row >> 1) & 3)) << 4));
        }
        __builtin_amdgcn_s_setprio(1);
#pragma unroll
        for (int mk = 0; mk < 4; ++mk)
#pragma unroll
            for (int nq = 0; nq < 4; ++nq)
                s[mk][nq] = MFMA16(kf[mk], qf[nq], zero4, 0, 0, 0);
        __builtin_amdgcn_s_setprio(0);
    }
    __builtin_amdgcn_sched_barrier(0);   // Q reads complete before VT overwrites Q

    // write VT[32][64] over Q slice (wave-private; in-wave DS ordering)
#pragma unroll
    for (int nv = 0; nv < 2; ++nv) {
        int d = nv * 16 + l15;
#pragma unroll
        for (int mt = 0; mt < 4; ++mt) {
            int tok = mt * 16 + lg * 4;
            *(int2*)(smem + hbase + vt_byte(d, tok)) = make_int2(vbf[mt][nv][0], vbf[mt][nv][1]);
        }
    }

    // prefetch bias+mask fragments (L2-hot, coalesced): bv4[mk][nq] over r
    float4 bv4[4][4];
    {
        const float4* bp = (const float4*)biasT + (wt * 6 + h) * 16 * 64 + ln;
#pragma unroll
        for (int mk = 0; mk < 4; ++mk)
#pragma unroll
            for (int nq = 0; nq < 4; ++nq)
                bv4[mk][nq] = bp[(mk * 4 + nq) * 64];
    }

    // ---------------- softmax over kt (no max pass: |C*s| << 1) ----------------
    // fused: w = pack(s*inv + bias) in one fmaf pass (bias/mask added post-softmax)
    const float C = 0.17677669529663687f * 1.4426950408889634f;  // scale * log2(e)
    int w[4][4][2];
#pragma unroll
    for (int nq = 0; nq < 4; ++nq) {
        float sum = 0.f;
#pragma unroll
        for (int mk = 0; mk < 4; ++mk)
#pragma unroll
            for (int r = 0; r < 4; ++r) {
                int kt = mk * 16 + lg * 4 + r;
                float e = (kt < 49) ? __builtin_amdgcn_exp2f(C * s[mk][nq][r]) : 0.0f;
                s[mk][nq][r] = e;
                sum += e;
            }
        sum += __shfl_xor(sum, 16);
        sum += __shfl_xor(sum, 32);
        float inv = __builtin_amdgcn_rcpf(sum);
#pragma unroll
        for (int mk = 0; mk < 4; ++mk) {
            float v0 = fmaf(s[mk][nq][0], inv, bv4[mk][nq].x);
            float v1 = fmaf(s[mk][nq][1], inv, bv4[mk][nq].y);
            float v2 = fmaf(s[mk][nq][2], inv, bv4[mk][nq].z);
            float v3 = fmaf(s[mk][nq][3], inv, bv4[mk][nq].w);
            w[mk][nq][0] = cvt_pk_bf16(v0, v1);
            w[mk][nq][1] = cvt_pk_bf16(v2, v3);
        }
    }

    // ---------------- O^T = VT * attn ----------------
    f32x4_t o[2][4];
#pragma unroll
    for (int md = 0; md < 2; ++md)
#pragma unroll
        for (int nq = 0; nq < 4; ++nq) o[md][nq] = zero4;

#if HAVE_MFMA_K16
    // w[mk][nq] is already a valid 16x16x16 B-operand (lane l15 = qt col, k = lg*4+r)
#pragma unroll
    for (int mk = 0; mk < 4; ++mk) {
        bf16x4_t vt2[2];
#pragma unroll
        for (int md = 0; md < 2; ++md) {
            int d = md * 16 + l15;
            vt2[md] = *(const bf16x4_t*)(smem + hbase + vt_byte(d, mk * 16 + lg * 4));
        }
        __builtin_amdgcn_s_setprio(1);
#pragma unroll
        for (int nq = 0; nq < 4; ++nq) {
            bf16x4_t wb = __builtin_bit_cast(bf16x4_t, make_int2(w[mk][nq][0], w[mk][nq][1]));
#pragma unroll
            for (int md = 0; md < 2; ++md)
                o[md][nq] = MFMA16K16(vt2[md], wb, o[md][nq], 0, 0, 0);
        }
        __builtin_amdgcn_s_setprio(0);
    }
#else
    // fallback: A staged per kt-half in dead K slice, K=32 MFMA
    const unsigned Abase = hbase + 4096;   // over K (dead after S)
#pragma unroll
    for (int ks = 0; ks < 2; ++ks) {
#pragma unroll
        for (int mh = 0; mh < 2; ++mh) {
            int mk = ks * 2 + mh;
            int d  = mh * 16 + lg * 4;
#pragma unroll
            for (int nq = 0; nq < 4; ++nq) {
                int qt = nq * 16 + l15;
                *(int2*)(smem + Abase + qk_byte(qt, d)) = make_int2(w[mk][nq][0], w[mk][nq][1]);
            }
        }
        __builtin_amdgcn_sched_barrier(0);   // A writes before reads
        bf16x8_t vf[2], bfr[4];
#pragma unroll
        for (int md = 0; md < 2; ++md) {
            int d = md * 16 + l15;
            vf[md] = *(const bf16x8_t*)(smem + hbase + d * 128 + (((ks * 4 + lg) ^ (d & 7)) << 4));
        }
#pragma unroll
        for (int nq = 0; nq < 4; ++nq) {
            int qt = nq * 16 + l15;
            bfr[nq] = *(const bf16x8_t*)(smem + Abase + qt * 64 + ((lg ^ ((qt >> 1) & 3)) << 4));
        }
        __builtin_amdgcn_s_setprio(1);
#pragma unroll
        for (int nq = 0; nq < 4; ++nq)
#pragma unroll
            for (int md = 0; md < 2; ++md)
                o[md][nq] = MFMA16(vf[md], bfr[nq], o[md][nq], 0, 0, 0);
        __builtin_amdgcn_s_setprio(0);
        __builtin_amdgcn_sched_barrier(0);   // half reads done before next-half writes
    }
#endif
    __syncthreads();   // #3: all done with slices; repurpose LDS for O

    // write O^T -> O_lds[qt][192ch] stride 400B, packed b64
#pragma unroll
    for (int md = 0; md < 2; ++md)
#pragma unroll
        for (int nq = 0; nq < 4; ++nq) {
            int qt = nq * 16 + l15;
            int ch = h * 32 + md * 16 + lg * 4;
            int d0 = cvt_pk_bf16(o[md][nq][0], o[md][nq][1]);
            int d1 = cvt_pk_bf16(o[md][nq][2], o[md][nq][3]);
            *(int2*)(smem + gbase + qt * 400 + ch * 2) = make_int2(d0, d1);
        }
    __syncthreads();   // #4: O ready

    // ---------------- proj: Y = O @ proj_w^T + b, wave owns 32 cols ----------------
    f32x4_t y[4][2];
#pragma unroll
    for (int mt = 0; mt < 4; ++mt) { y[mt][0] = zero4; y[mt][1] = zero4; }
#pragma unroll
    for (int ks = 0; ks < 6; ++ks) {
        bf16x8_t aa[4], bb[2];
#pragma unroll
        for (int mt = 0; mt < 4; ++mt)
            aa[mt] = *(const bf16x8_t*)(smem + gbase + (mt * 16 + l15) * 400 + (ks * 32 + lg * 8) * 2);
#pragma unroll
        for (int nt = 0; nt < 2; ++nt)
            bb[nt] = *(const bf16x8_t*)(wprojT + (h * 32 + nt * 16 + l15) * 192 + ks * 32 + lg * 8);
        __builtin_amdgcn_s_setprio(1);
#pragma unroll
        for (int mt = 0; mt < 4; ++mt)
#pragma unroll
            for (int nt = 0; nt < 2; ++nt)
                y[mt][nt] = MFMA16(aa[mt], bb[nt], y[mt][nt], 0, 0, 0);
        __builtin_amdgcn_s_setprio(0);
    }
    // epilogue: +proj_b, scatter via precomputed rowOff
    float pb0 = proj_b[h * 32 + l15];
    float pb1 = proj_b[h * 32 + 16 + l15];
#pragma unroll
    for (int mt = 0; mt < 4; ++mt)
#pragma unroll
        for (int r = 0; r < 4; ++r) {
            int row = mt * 16 + lg * 4 + r;
            if (row < 49) {
                int ro = rowOff[row];
                out[ro + h * 32 + l15]      = y[mt][0][r] + pb0;
                out[ro + h * 32 + 16 + l15] = y[mt][1][r] + pb1;
            }
        }
}

extern "C" void kernel_launch(void* const* d_in, const int* in_sizes, int n_in,
                              void* d_out, int out_size, void* d_ws, size_t ws_size,
                              hipStream_t stream) {
    const float* x         = (const float*)d_in[0];
    const float* qkv_w     = (const float*)d_in[1];
    const float* qkv_b     = (const float*)d_in[2];
    const float* rel_table = (const float*)d_in[3];
    const float* proj_w    = (const float*)d_in[4];
    const float* proj_b    = (const float*)d_in[5];
    float* out = (float*)d_out;

    unsigned short* wqkvT  = (unsigned short*)d_ws;            // [576][192] bf16 = 221184 B
    unsigned short* wprojT = wqkvT + 576 * 192;                // [192][192] bf16 =  73728 B
    float* biasT = (float*)((char*)d_ws + 294912);             // [4][6][16][64] float4 = 393216 B

    prep_weights<<<576, 256, 0, stream>>>(qkv_w, proj_w, wqkvT, wprojT);
    prep_bias<<<96, 256, 0, stream>>>(rel_table, biasT);
    swin_fused<<<2048, 768, 0, stream>>>(x, qkv_b, proj_b, wqkvT, wprojT, biasT, out);
}

// Round 12
// 253.461 us; speedup vs baseline: 1.8273x; 1.0956x over previous
//
#include <hip/hip_runtime.h>
#include <hip/hip_bf16.h>

typedef __attribute__((ext_vector_type(8))) short bf16x8_t;
typedef __attribute__((ext_vector_type(4))) short bf16x4_t;
typedef __attribute__((ext_vector_type(4))) float f32x4_t;

#define MFMA16 __builtin_amdgcn_mfma_f32_16x16x32_bf16

#if __has_builtin(__builtin_amdgcn_mfma_f32_16x16x16bf16_1k)
#define HAVE_MFMA_K16 1
#define MFMA16K16 __builtin_amdgcn_mfma_f32_16x16x16bf16_1k
#else
#define HAVE_MFMA_K16 0
#endif

__device__ __forceinline__ unsigned short f2bf(float f) {
    return __builtin_bit_cast(unsigned short, __float2bfloat16(f));
}
__device__ __forceinline__ int cvt_pk_bf16(float lo, float hi) {
    int r;
    asm("v_cvt_pk_bf16_f32 %0, %1, %2" : "=v"(r) : "v"(lo), "v"(hi));
    return r;
}

// ---------------- LDS layout: 2 window-groups, one window per group ----------------
// Per group g:
//   slices @ g*49152, per head h @ +h*8192: Q[64][32e] swz | K[64][32e] swz
//     (VT over Q post-S; O[64 rows][192ch] stride 400 over the slices region post-#3)
//   X[64][192] bf16 stride 400B @ XB_OFF + g*25600 (dedicated; no X<->slice alias
//     -> r4's barrier #2 deleted; waves drift freely between #1 and #3)
// rowOff[g][64] int @ ROWOFF_OFF.  150016 B -> 1 block/CU (register-limited to 12
// waves anyway).
//
// This is r4 (231.5us, best) + two individually-validated register-neutral deltas:
//   (a) dedicated X -> one fewer sync point (r9/r10/r11 validated the layout);
//   (b) hardware __syncthreads instead of LDS-atomic spin barriers (r10/r11
//       validated; groups are naturally phase-locked, which r9 showed is GOOD).
// Register law (6x confirmed r1/r2/r5-r8/r10): peak live >~165 VGPRs => whole-array
// spill => ~500MB scratch. Nothing here adds live state vs r4.
// Stage-hiding verdict (r5-r8, r10, r11): exposing the stage HBM latency is
// cheaper than any structure that hides it. Stage stays inline and exposed.
#define XB_OFF     98304
#define ROWOFF_OFF 149504
#define SMEM_BYTES 150016

__device__ __forceinline__ int qk_byte(int row, int d) {
    return row * 64 + ((((d >> 3) ^ ((row >> 1) & 3)) << 4) | ((d & 7) << 1));
}
__device__ __forceinline__ int vt_byte(int d, int tok) {
    return d * 128 + ((((tok >> 3) ^ (d & 7)) << 4) | ((tok & 7) << 1));
}

__global__ void prep_weights(const float* __restrict__ qkv_w, const float* __restrict__ proj_w,
                             unsigned short* __restrict__ wqkvT, unsigned short* __restrict__ wprojT)
{
    int i = blockIdx.x * 256 + threadIdx.x;
    if (i < 576 * 192) {            // wqkvT[n][k] = qkv_w[k][n]
        int n = i / 192, k = i - n * 192;
        wqkvT[i] = f2bf(qkv_w[k * 576 + n]);
    }
    if (i < 192 * 192) {            // wprojT[n][k] = proj_w[k][n]
        int n = i / 192, k = i - n * 192;
        wprojT[i] = f2bf(proj_w[k * 192 + n]);
    }
}

// biasT[wt][h][frag=mk*4+nq][lane] = float4 over r (0 outside 49x49)
__global__ void prep_bias(const float* __restrict__ rel_table, float* __restrict__ biasT)
{
    int i = blockIdx.x * 256 + threadIdx.x;    // 0..24575
    if (i >= 4 * 6 * 16 * 64) return;
    int ln  = i & 63;
    int f   = (i >> 6) & 15;
    int h   = (i >> 10) % 6;
    int wt  = i / 6144;                        // 0..3 = borderH*2 + borderW
    int l15 = ln & 15, lg = ln >> 4;
    int mk  = f >> 2, nq = f & 3;
    int qt  = nq * 16 + l15;
    bool bh = (wt & 2) != 0, bw = (wt & 1) != 0;
    float4 o = {0.f, 0.f, 0.f, 0.f};
    float* po = (float*)&o;
    int iq = qt / 7, jq = qt - iq * 7;
    int regq = (bh ? ((iq < 4) ? 3 : 6) : 0) + (bw ? ((jq < 4) ? 1 : 2) : 0);
    for (int r = 0; r < 4; ++r) {
        int kt = mk * 16 + lg * 4 + r;
        if (kt < 49 && qt < 49) {
            int ik = kt / 7, jk = kt - ik * 7;
            int idx = (iq - ik + 6) * 13 + (jq - jk + 6);
            int regk = (bh ? ((ik < 4) ? 3 : 6) : 0) + (bw ? ((jk < 4) ? 1 : 2) : 0);
            po[r] = rel_table[idx * 6 + h] + ((regk != regq) ? -100.0f : 0.0f);
        }
    }
    ((float4*)biasT)[i] = o;
}

__global__ __launch_bounds__(768, 3)
void swin_fused(const float* __restrict__ x,
                const float* __restrict__ qkv_b,
                const float* __restrict__ proj_b,
                const unsigned short* __restrict__ wqkvT,
                const unsigned short* __restrict__ wprojT,
                const float* __restrict__ biasT,
                float* __restrict__ out)
{
    __shared__ unsigned char smem[SMEM_BYTES];

    const int tid = threadIdx.x;
    const int wv  = tid >> 6;          // 0..11
    const int g   = (wv >= 6) ? 1 : 0; // window group within block
    const int h   = wv - 6 * g;        // head 0..5
    const int ln  = tid & 63;
    const int l15 = ln & 15;
    const int lg  = ln >> 4;           // 0..3
    const int tg  = tid - g * 384;     // thread id within group, 0..383

    const int bw  = blockIdx.x * 2 + g;    // window id 0..4095
    const int b   = bw >> 6;
    const int win = bw & 63;
    const int wh  = win >> 3;
    const int ww  = win & 7;
    const int wt  = ((wh == 7) ? 2 : 0) | ((ww == 7) ? 1 : 0);

    const unsigned gbase = g * 49152;
    const unsigned hbase = gbase + h * 8192;
    const unsigned xb    = XB_OFF + g * 25600;
    int* rowOff = (int*)(smem + ROWOFF_OFF + g * 256);
    const f32x4_t zero4 = {0.f, 0.f, 0.f, 0.f};

    // ---------------- stage shifted-window X -> dedicated LDS buffer ----------------
#pragma unroll
    for (int it = 0; it < 8; ++it) {
        int idx = tg + it * 384;              // 64 rows * 48 4-elem chunks
        int n   = idx / 48;
        int c4  = idx - n * 48;
        int2* dst = (int2*)(smem + xb + n * 400 + c4 * 8);
        if (n < 49) {
            int i = n / 7, j = n - i * 7;
            int sh = wh * 7 + i + 3; if (sh >= 56) sh -= 56;
            int sw = ww * 7 + j + 3; if (sw >= 56) sw -= 56;
            int ro = ((b * 56 + sh) * 56 + sw) * 192;
            if (c4 == 0) rowOff[n] = ro;
            const float4* src = (const float4*)(x + ro + c4 * 4);
            float4 v = *src;
            int2 p;
            p.x = cvt_pk_bf16(v.x, v.y);
            p.y = cvt_pk_bf16(v.z, v.w);
            *dst = p;
        } else {
            *dst = make_int2(0, 0);
        }
    }
    __syncthreads();   // #1: X + rowOff visible

    // ---------------- merged QKV GEMM: one X pass, nt = [q0,q1,k0,k1,v0,v1] ----------------
    f32x4_t accq[4][6];
#pragma unroll
    for (int mt = 0; mt < 4; ++mt)
#pragma unroll
        for (int nt = 0; nt < 6; ++nt) accq[mt][nt] = zero4;
#pragma unroll
    for (int ks = 0; ks < 6; ++ks) {
        bf16x8_t af[4];
#pragma unroll
        for (int mt = 0; mt < 4; ++mt)
            af[mt] = *(const bf16x8_t*)(smem + xb + (mt * 16 + l15) * 400 + (ks * 32 + lg * 8) * 2);
        bf16x8_t bfv[6];
#pragma unroll
        for (int nt = 0; nt < 6; ++nt)
            bfv[nt] = *(const bf16x8_t*)(wqkvT + ((nt >> 1) * 192 + h * 32 + (nt & 1) * 16 + l15) * 192 + ks * 32 + lg * 8);
        __builtin_amdgcn_s_setprio(1);
#pragma unroll
        for (int nt = 0; nt < 6; ++nt)
#pragma unroll
            for (int mt = 0; mt < 4; ++mt)
                accq[mt][nt] = MFMA16(af[mt], bfv[nt], accq[mt][nt], 0, 0, 0);
        __builtin_amdgcn_s_setprio(0);
    }
    // pack V to bf16 (+bias) -> 16 dwords held in regs through S phase
    int vbf[4][2][2];
#pragma unroll
    for (int nv = 0; nv < 2; ++nv) {
        float bb = qkv_b[384 + h * 32 + nv * 16 + l15];
#pragma unroll
        for (int mt = 0; mt < 4; ++mt) {
            vbf[mt][nv][0] = cvt_pk_bf16(accq[mt][4 + nv][0] + bb, accq[mt][4 + nv][1] + bb);
            vbf[mt][nv][1] = cvt_pk_bf16(accq[mt][4 + nv][2] + bb, accq[mt][4 + nv][3] + bb);
        }
    }
    // (no barrier #2: X is dedicated; everything below until #3 touches only this
    //  wave's private head slice or read-only data -> waves drift freely)

    // scatter Q,K (+bias, bf16) into wave-private slice
#pragma unroll
    for (int nt = 0; nt < 4; ++nt) {
        int part = nt >> 1;                    // 0=q, 1=k
        int d    = (nt & 1) * 16 + l15;
        float bb = qkv_b[part * 192 + h * 32 + d];
        unsigned base = hbase + part * 4096;
#pragma unroll
        for (int mt = 0; mt < 4; ++mt)
#pragma unroll
            for (int r = 0; r < 4; ++r) {
                int row = mt * 16 + lg * 4 + r;
                *(unsigned short*)(smem + base + qk_byte(row, d)) = f2bf(accq[mt][nt][r] + bb);
            }
    }
    __builtin_amdgcn_sched_barrier(0);   // keep S-reads after scatter writes

    // ---------------- S^T = K Q^T (wave-private, rows=kt, cols=qt) ----------------
    f32x4_t s[4][4];
    {
        bf16x8_t kf[4], qf[4];
#pragma unroll
        for (int mk = 0; mk < 4; ++mk) {
            int row = mk * 16 + l15;
            kf[mk] = *(const bf16x8_t*)(smem + hbase + 4096 + row * 64 + ((lg ^ ((row >> 1) & 3)) << 4));
        }
#pragma unroll
        for (int nq = 0; nq < 4; ++nq) {
            int row = nq * 16 + l15;
            qf[nq] = *(const bf16x8_t*)(smem + hbase + row * 64 + ((lg ^ ((row >> 1) & 3)) << 4));
        }
        __builtin_amdgcn_s_setprio(1);
#pragma unroll
        for (int mk = 0; mk < 4; ++mk)
#pragma unroll
            for (int nq = 0; nq < 4; ++nq)
                s[mk][nq] = MFMA16(kf[mk], qf[nq], zero4, 0, 0, 0);
        __builtin_amdgcn_s_setprio(0);
    }
    __builtin_amdgcn_sched_barrier(0);   // Q reads complete before VT overwrites Q

    // write VT[32][64] over Q slice (wave-private; in-wave DS ordering)
#pragma unroll
    for (int nv = 0; nv < 2; ++nv) {
        int d = nv * 16 + l15;
#pragma unroll
        for (int mt = 0; mt < 4; ++mt) {
            int tok = mt * 16 + lg * 4;
            *(int2*)(smem + hbase + vt_byte(d, tok)) = make_int2(vbf[mt][nv][0], vbf[mt][nv][1]);
        }
    }

    // prefetch bias+mask fragments (L2-hot, coalesced): bv4[mk][nq] over r
    float4 bv4[4][4];
    {
        const float4* bp = (const float4*)biasT + (wt * 6 + h) * 16 * 64 + ln;
#pragma unroll
        for (int mk = 0; mk < 4; ++mk)
#pragma unroll
            for (int nq = 0; nq < 4; ++nq)
                bv4[mk][nq] = bp[(mk * 4 + nq) * 64];
    }

    // ---------------- softmax over kt (no max pass: |C*s| << 1) ----------------
    // fused: w = pack(s*inv + bias) in one fmaf pass (bias/mask added post-softmax)
    const float C = 0.17677669529663687f * 1.4426950408889634f;  // scale * log2(e)
    int w[4][4][2];
#pragma unroll
    for (int nq = 0; nq < 4; ++nq) {
        float sum = 0.f;
#pragma unroll
        for (int mk = 0; mk < 4; ++mk)
#pragma unroll
            for (int r = 0; r < 4; ++r) {
                int kt = mk * 16 + lg * 4 + r;
                float e = (kt < 49) ? __builtin_amdgcn_exp2f(C * s[mk][nq][r]) : 0.0f;
                s[mk][nq][r] = e;
                sum += e;
            }
        sum += __shfl_xor(sum, 16);
        sum += __shfl_xor(sum, 32);
        float inv = __builtin_amdgcn_rcpf(sum);
#pragma unroll
        for (int mk = 0; mk < 4; ++mk) {
            float v0 = fmaf(s[mk][nq][0], inv, bv4[mk][nq].x);
            float v1 = fmaf(s[mk][nq][1], inv, bv4[mk][nq].y);
            float v2 = fmaf(s[mk][nq][2], inv, bv4[mk][nq].z);
            float v3 = fmaf(s[mk][nq][3], inv, bv4[mk][nq].w);
            w[mk][nq][0] = cvt_pk_bf16(v0, v1);
            w[mk][nq][1] = cvt_pk_bf16(v2, v3);
        }
    }

    // ---------------- O^T = VT * attn ----------------
    f32x4_t o[2][4];
#pragma unroll
    for (int md = 0; md < 2; ++md)
#pragma unroll
        for (int nq = 0; nq < 4; ++nq) o[md][nq] = zero4;

#if HAVE_MFMA_K16
    // w[mk][nq] is already a valid 16x16x16 B-operand (lane l15 = qt col, k = lg*4+r)
#pragma unroll
    for (int mk = 0; mk < 4; ++mk) {
        bf16x4_t vt2[2];
#pragma unroll
        for (int md = 0; md < 2; ++md) {
            int d = md * 16 + l15;
            vt2[md] = *(const bf16x4_t*)(smem + hbase + vt_byte(d, mk * 16 + lg * 4));
        }
        __builtin_amdgcn_s_setprio(1);
#pragma unroll
        for (int nq = 0; nq < 4; ++nq) {
            bf16x4_t wb = __builtin_bit_cast(bf16x4_t, make_int2(w[mk][nq][0], w[mk][nq][1]));
#pragma unroll
            for (int md = 0; md < 2; ++md)
                o[md][nq] = MFMA16K16(vt2[md], wb, o[md][nq], 0, 0, 0);
        }
        __builtin_amdgcn_s_setprio(0);
    }
#else
    // fallback: A staged per kt-half in dead K slice, K=32 MFMA
    const unsigned Abase = hbase + 4096;   // over K (dead after S)
#pragma unroll
    for (int ks = 0; ks < 2; ++ks) {
#pragma unroll
        for (int mh = 0; mh < 2; ++mh) {
            int mk = ks * 2 + mh;
            int d  = mh * 16 + lg * 4;
#pragma unroll
            for (int nq = 0; nq < 4; ++nq) {
                int qt = nq * 16 + l15;
                *(int2*)(smem + Abase + qk_byte(qt, d)) = make_int2(w[mk][nq][0], w[mk][nq][1]);
            }
        }
        __builtin_amdgcn_sched_barrier(0);   // A writes before reads
        bf16x8_t vf[2], bfr[4];
#pragma unroll
        for (int md = 0; md < 2; ++md) {
            int d = md * 16 + l15;
            vf[md] = *(const bf16x8_t*)(smem + hbase + d * 128 + (((ks * 4 + lg) ^ (d & 7)) << 4));
        }
#pragma unroll
        for (int nq = 0; nq < 4; ++nq) {
            int qt = nq * 16 + l15;
            bfr[nq] = *(const bf16x8_t*)(smem + Abase + qt * 64 + ((lg ^ ((qt >> 1) & 3)) << 4));
        }
        __builtin_amdgcn_s_setprio(1);
#pragma unroll
        for (int nq = 0; nq < 4; ++nq)
#pragma unroll
            for (int md = 0; md < 2; ++md)
                o[md][nq] = MFMA16(vf[md], bfr[nq], o[md][nq], 0, 0, 0);
        __builtin_amdgcn_s_setprio(0);
        __builtin_amdgcn_sched_barrier(0);   // half reads done before next-half writes
    }
#endif
    __syncthreads();   // #3: all done with slices; repurpose LDS for O

    // write O^T -> O_lds[qt][192ch] stride 400B, packed b64
#pragma unroll
    for (int md = 0; md < 2; ++md)
#pragma unroll
        for (int nq = 0; nq < 4; ++nq) {
            int qt = nq * 16 + l15;
            int ch = h * 32 + md * 16 + lg * 4;
            int d0 = cvt_pk_bf16(o[md][nq][0], o[md][nq][1]);
            int d1 = cvt_pk_bf16(o[md][nq][2], o[md][nq][3]);
            *(int2*)(smem + gbase + qt * 400 + ch * 2) = make_int2(d0, d1);
        }
    __syncthreads();   // #4: O ready

    // ---------------- proj: Y = O @ proj_w^T + b, wave owns 32 cols ----------------
    f32x4_t y[4][2];
#pragma unroll
    for (int mt = 0; mt < 4; ++mt) { y[mt][0] = zero4; y[mt][1] = zero4; }
#pragma unroll
    for (int ks = 0; ks < 6; ++ks) {
        bf16x8_t aa[4], bb[2];
#pragma unroll
        for (int mt = 0; mt < 4; ++mt)
            aa[mt] = *(const bf16x8_t*)(smem + gbase + (mt * 16 + l15) * 400 + (ks * 32 + lg * 8) * 2);
#pragma unroll
        for (int nt = 0; nt < 2; ++nt)
            bb[nt] = *(const bf16x8_t*)(wprojT + (h * 32 + nt * 16 + l15) * 192 + ks * 32 + lg * 8);
        __builtin_amdgcn_s_setprio(1);
#pragma unroll
        for (int mt = 0; mt < 4; ++mt)
#pragma unroll
            for (int nt = 0; nt < 2; ++nt)
                y[mt][nt] = MFMA16(aa[mt], bb[nt], y[mt][nt], 0, 0, 0);
        __builtin_amdgcn_s_setprio(0);
    }
    // epilogue: +proj_b, scatter via precomputed rowOff
    float pb0 = proj_b[h * 32 + l15];
    float pb1 = proj_b[h * 32 + 16 + l15];
#pragma unroll
    for (int mt = 0; mt < 4; ++mt)
#pragma unroll
        for (int r = 0; r < 4; ++r) {
            int row = mt * 16 + lg * 4 + r;
            if (row < 49) {
                int ro = rowOff[row];
                out[ro + h * 32 + l15]      = y[mt][0][r] + pb0;
                out[ro + h * 32 + 16 + l15] = y[mt][1][r] + pb1;
            }
        }
}

extern "C" void kernel_launch(void* const* d_in, const int* in_sizes, int n_in,
                              void* d_out, int out_size, void* d_ws, size_t ws_size,
                              hipStream_t stream) {
    const float* x         = (const float*)d_in[0];
    const float* qkv_w     = (const float*)d_in[1];
    const float* qkv_b     = (const float*)d_in[2];
    const float* rel_table = (const float*)d_in[3];
    const float* proj_w    = (const float*)d_in[4];
    const float* proj_b    = (const float*)d_in[5];
    float* out = (float*)d_out;

    unsigned short* wqkvT  = (unsigned short*)d_ws;            // [576][192] bf16 = 221184 B
    unsigned short* wprojT = wqkvT + 576 * 192;                // [192][192] bf16 =  73728 B
    float* biasT = (float*)((char*)d_ws + 294912);             // [4][6][16][64] float4 = 393216 B

    prep_weights<<<576, 256, 0, stream>>>(qkv_w, proj_w, wqkvT, wprojT);
    prep_bias<<<96, 256, 0, stream>>>(rel_table, biasT);
    swin_fused<<<2048, 768, 0, stream>>>(x, qkv_b, proj_b, wqkvT, wprojT, biasT, out);
}